// Round 13
// baseline (182.316 us; speedup 1.0000x reference)
//
#include <hip/hip_runtime.h>

#define B_SZ 4
#define LQ 4096
#define LKV 4096
#define DIN 256
#define DOUT 128
#define KVBLK 32
#define NT (LKV / KVBLK)
#define BLQ (B_SZ * LQ)
#define KTILE (KVBLK * 128)  // u16 elements per K or V tile (8 KB)

typedef unsigned short u16;
typedef __attribute__((ext_vector_type(8))) short bf16x8;
typedef __attribute__((ext_vector_type(4))) float f32x4;
typedef __attribute__((ext_vector_type(16))) float f32x16;
typedef __attribute__((ext_vector_type(2))) unsigned uint2v;
typedef __attribute__((ext_vector_type(4))) unsigned uint4v;

union Bf8Pack {
  u16 u[8];
  bf16x8 v;
};
union U16x4Pack {
  u16 u[4];
  uint2 v;
};
union PFrag {
  unsigned u[4];
  bf16x8 v;
};

__device__ __forceinline__ u16 f2bf(float x) {
  unsigned u = __float_as_uint(x);
  u += 0x7fffu + ((u >> 16) & 1u);
  return (u16)(u >> 16);
}

__device__ __forceinline__ float bf2f(u16 x) {
  return __uint_as_float(((unsigned)x) << 16);
}

__device__ __forceinline__ unsigned cvt_pk_bf16(float lo, float hi) {
  unsigned r;
  asm("v_cvt_pk_bf16_f32 %0, %1, %2" : "=v"(r) : "v"(lo), "v"(hi));
  return r;
}

__device__ __forceinline__ void gload_lds16(const u16* g, u16* l) {
  __builtin_amdgcn_global_load_lds(
      (__attribute__((address_space(1))) unsigned int*)g,
      (__attribute__((address_space(3))) unsigned int*)l, 16, 0, 0);
}

// ---------- weight transpose + bf16 convert: Wt[3][128][256], WoT[128][128] ----------
__global__ __launch_bounds__(256) void wtrans_kernel(
    const float* __restrict__ Wq, const float* __restrict__ Wk,
    const float* __restrict__ Wv, const float* __restrict__ Wo,
    u16* __restrict__ Wt, u16* __restrict__ WoT) {
  const int gid = blockIdx.x * 256 + threadIdx.x;
  if (gid < 3 * DOUT * DIN) {
    const int which = gid / (DOUT * DIN);
    const int r = gid % (DOUT * DIN);
    const int n = r >> 8;
    const int k = r & 255;
    const float* W = (which == 0) ? Wq : (which == 1) ? Wk : Wv;
    Wt[gid] = f2bf(W[k * DOUT + n]);
  } else {
    const int r = gid - 3 * DOUT * DIN;
    if (r < DOUT * DOUT) {
      const int n = r >> 7;
      const int k = r & 127;
      WoT[r] = f2bf(Wo[k * DOUT + n]);
    }
  }
}

// ---------- QKV projection via MFMA (r8 3-way form: restores L2 handoff) ----------
__global__ __launch_bounds__(256) void qkv_proj_mfma(
    const float* __restrict__ ligand, const float* __restrict__ pocket,
    const float* __restrict__ bq, const float* __restrict__ bk,
    const float* __restrict__ bv, const u16* __restrict__ Wt,
    u16* __restrict__ Qb, u16* __restrict__ Kb, u16* __restrict__ Vt) {
  const int which = blockIdx.y;
  const int row0 = blockIdx.x * 64;
  const int tid = threadIdx.x;
  const int wid = tid >> 6;
  const int lane = tid & 63;
  const int lg = lane >> 4, lr = lane & 15;
  const float* __restrict__ src = (which == 0) ? ligand : pocket;
  const int m = row0 + wid * 16 + lr;

  bf16x8 sfrag[8];
#pragma unroll
  for (int ks = 0; ks < 8; ++ks) {
    const float* p = src + (size_t)m * DIN + ks * 32 + lg * 8;
    const float4 a = *(const float4*)p;
    const float4 b = *(const float4*)(p + 4);
    Bf8Pack pk;
    pk.u[0] = f2bf(a.x); pk.u[1] = f2bf(a.y); pk.u[2] = f2bf(a.z); pk.u[3] = f2bf(a.w);
    pk.u[4] = f2bf(b.x); pk.u[5] = f2bf(b.y); pk.u[6] = f2bf(b.z); pk.u[7] = f2bf(b.w);
    sfrag[ks] = pk.v;
  }

  if (which < 2) {
    const float* __restrict__ bias = (which == 0) ? bq : bk;
    u16* __restrict__ dst = (which == 0) ? Qb : Kb;
    const u16* __restrict__ Wtw = Wt + (size_t)which * DOUT * DIN;
    // Q pre-scaled by 1/sqrt(128) * log2(e): flash uses exp2 with fixed m=0.
    const float qscale = (float)(0.08838834764831845 * 1.4426950408889634);
#pragma unroll
    for (int dt = 0; dt < 8; ++dt) {
      f32x4 acc = (f32x4){0.f, 0.f, 0.f, 0.f};
#pragma unroll
      for (int ks = 0; ks < 8; ++ks) {
        const bf16x8 wf =
            *(const bf16x8*)(Wtw + (size_t)(dt * 16 + lr) * DIN + ks * 32 + lg * 8);
        acc = __builtin_amdgcn_mfma_f32_16x16x32_bf16(wf, sfrag[ks], acc, 0, 0, 0);
      }
      U16x4Pack st;
#pragma unroll
      for (int j = 0; j < 4; ++j) {
        float v = acc[j] + bias[dt * 16 + lg * 4 + j];
        if (which == 0) v *= qscale;
        st.u[j] = f2bf(v);
      }
      *(uint2*)(dst + (size_t)m * DOUT + dt * 16 + lg * 4) = st.v;
    }
  } else {
    // V: C[m][d] orientation, transposed output V^T[d][kv]
    const u16* __restrict__ Wtv = Wt + 2 * DOUT * DIN;
    const int batch = row0 >> 12;
    const int kvbase = (row0 & 4095) + wid * 16 + lg * 4;
#pragma unroll
    for (int dt = 0; dt < 8; ++dt) {
      f32x4 acc = (f32x4){0.f, 0.f, 0.f, 0.f};
#pragma unroll
      for (int ks = 0; ks < 8; ++ks) {
        const bf16x8 wf =
            *(const bf16x8*)(Wtv + (size_t)(dt * 16 + lr) * DIN + ks * 32 + lg * 8);
        acc = __builtin_amdgcn_mfma_f32_16x16x32_bf16(sfrag[ks], wf, acc, 0, 0, 0);
      }
      const int d = dt * 16 + lr;
      const float b = bv[d];
      U16x4Pack st;
#pragma unroll
      for (int j = 0; j < 4; ++j) st.u[j] = f2bf(acc[j] + b);
      *(uint2*)(Vt + ((size_t)batch * DOUT + d) * LKV + kvbase) = st.v;
    }
  }
}

// ---------------- Flash attention: r8 byte-exact core (32x32x16, P in-register,
// double-buffer, one __syncthreads/iter, shfl_xor row-sum) + NT-store epilogue.
__global__ __launch_bounds__(256, 4) void flash_attn_kernel(
    const u16* __restrict__ Qb, const u16* __restrict__ Kb,
    const u16* __restrict__ Vt, u16* __restrict__ Opart,
    float* __restrict__ Lsum, int niter) {
  __shared__ __align__(16) u16 Ks[2 * KTILE];
  __shared__ __align__(16) u16 Vs[2 * KTILE];

  const int batch = blockIdx.y;
  const int split = blockIdx.z;
  const int q0 = blockIdx.x * 128;
  const int tid = threadIdx.x;
  const int wid = tid >> 6;
  const int lane = tid & 63;
  const int ql = lane & 31;
  const int h = lane >> 5;
  const int t0 = split * niter;

  // staging source offsets (u16 elements): 512 chunks/tile, 2 per thread
  int koff[2], voff[2];
#pragma unroll
  for (int i = 0; i < 2; ++i) {
    const int c = i * 256 + tid;
    koff[i] = (c & 31) * 128 + (c >> 6) * 16 + ((c >> 5) & 1) * 8;
    voff[i] = ((c >> 7) * 32 + (c & 31)) * LKV + (((c >> 6) & 1) << 4) +
              (((c >> 5) & 1) << 3);
  }
  const u16* KbB = Kb + (size_t)batch * LKV * 128 + (size_t)t0 * KTILE;
  const u16* VtB = Vt + (size_t)batch * 128 * LKV + t0 * KVBLK;

#define STAGEKV(buf, t)                                                      \
  {                                                                          \
    _Pragma("unroll") for (int i = 0; i < 2; ++i)                            \
        gload_lds16(KbB + (t) * KTILE + koff[i],                             \
                    Ks + (buf) * KTILE + (i * 256 + tid) * 8);               \
    _Pragma("unroll") for (int i = 0; i < 2; ++i)                            \
        gload_lds16(VtB + (t) * KVBLK + voff[i],                             \
                    Vs + (buf) * KTILE + (i * 256 + tid) * 8);               \
  }

  // Q fragments: lane holds Q[q0+wid*32+ql][ks*16 + h*8 ..+8], ks=0..7
  const u16* Qw = Qb + ((size_t)batch * LQ + q0 + wid * 32) * 128;
  bf16x8 qf[8];
#pragma unroll
  for (int ks = 0; ks < 8; ++ks)
    qf[ks] = *(const bf16x8*)(Qw + (size_t)ql * 128 + ks * 16 + h * 8);

  f32x16 oacc[4];
#pragma unroll
  for (int dt = 0; dt < 4; ++dt)
#pragma unroll
    for (int r = 0; r < 16; ++r) oacc[dt][r] = 0.f;
  float l_run = 0.f;

  STAGEKV(0, 0);
  __syncthreads();

  int cur = 0;
  for (int t = 0; t < niter; ++t) {
    if (t + 1 < niter) STAGEKV(cur ^ 1, t + 1);

    const u16* kread = Ks + cur * KTILE + lane * 8;
    const u16* vread = Vs + cur * KTILE + lane * 8;

    // S = K · Q^T  (D[kv][q], col q = lane&31)
    f32x16 sacc;
#pragma unroll
    for (int r = 0; r < 16; ++r) sacc[r] = 0.f;
#pragma unroll
    for (int ks = 0; ks < 8; ++ks) {
      const bf16x8 kf = *(const bf16x8*)(kread + ks * 512);
      sacc = __builtin_amdgcn_mfma_f32_32x32x16_bf16(kf, qf[ks], sacc, 0, 0, 0);
    }

    // fixed-m softmax (log2 domain): p = exp2(s); pairwise tree sum
    float p[16];
#pragma unroll
    for (int r = 0; r < 16; ++r) p[r] = exp2f(sacc[r]);
    float rs = (((p[0] + p[1]) + (p[2] + p[3])) + ((p[4] + p[5]) + (p[6] + p[7]))) +
               (((p[8] + p[9]) + (p[10] + p[11])) + ((p[12] + p[13]) + (p[14] + p[15])));
    rs += __shfl_xor(rs, 32, 64);
    l_run += rs;

    // pack P to bf16 pairs, redistribute halves via permlane32_swap
    unsigned w0 = cvt_pk_bf16(p[0], p[1]);
    unsigned w1 = cvt_pk_bf16(p[2], p[3]);
    unsigned w2 = cvt_pk_bf16(p[4], p[5]);
    unsigned w3 = cvt_pk_bf16(p[6], p[7]);
    unsigned w4 = cvt_pk_bf16(p[8], p[9]);
    unsigned w5 = cvt_pk_bf16(p[10], p[11]);
    unsigned w6 = cvt_pk_bf16(p[12], p[13]);
    unsigned w7 = cvt_pk_bf16(p[14], p[15]);
    asm("v_permlane32_swap_b32 %0, %1" : "+v"(w0), "+v"(w2));
    asm("v_permlane32_swap_b32 %0, %1" : "+v"(w1), "+v"(w3));
    asm("v_permlane32_swap_b32 %0, %1" : "+v"(w4), "+v"(w6));
    asm("v_permlane32_swap_b32 %0, %1" : "+v"(w5), "+v"(w7));
    PFrag pa0, pa1;
    pa0.u[0] = w0; pa0.u[1] = w1; pa0.u[2] = w2; pa0.u[3] = w3;  // kv 0..15
    pa1.u[0] = w4; pa1.u[1] = w5; pa1.u[2] = w6; pa1.u[3] = w7;  // kv 16..31

    // O^T += V^T · P^T
#pragma unroll
    for (int dt = 0; dt < 4; ++dt) {
      const bf16x8 vf0 = *(const bf16x8*)(vread + (dt * 2 + 0) * 512);
      oacc[dt] = __builtin_amdgcn_mfma_f32_32x32x16_bf16(vf0, pa0.v, oacc[dt], 0, 0, 0);
      const bf16x8 vf1 = *(const bf16x8*)(vread + (dt * 2 + 1) * 512);
      oacc[dt] = __builtin_amdgcn_mfma_f32_32x32x16_bf16(vf1, pa1.v, oacc[dt], 0, 0, 0);
    }

    __syncthreads();
    cur ^= 1;
  }

  // write bf16 unnormalized partials + row sums (m = 0 global) — NON-TEMPORAL:
  // the 32 MB partial stream must hit HBM anyway; keep it from evicting K/V/Q.
  const size_t rowbase = (size_t)split * BLQ + (size_t)batch * LQ + q0 + wid * 32;
  u16* Op = Opart + (rowbase + ql) * 128;
#pragma unroll
  for (int dt = 0; dt < 4; ++dt)
#pragma unroll
    for (int g2 = 0; g2 < 4; ++g2) {
      uint2v st;
      st.x = cvt_pk_bf16(oacc[dt][g2 * 4 + 0], oacc[dt][g2 * 4 + 1]);
      st.y = cvt_pk_bf16(oacc[dt][g2 * 4 + 2], oacc[dt][g2 * 4 + 3]);
      __builtin_nontemporal_store(st, (uint2v*)(Op + dt * 32 + g2 * 8 + h * 4));
    }
  if (lane < 32) __builtin_nontemporal_store(l_run, &Lsum[rowbase + lane]);
#undef STAGEKV
}

// ---------- combine KV-splits (linear, m=0) + output projection via MFMA ----------
template <int NS>
__global__ __launch_bounds__(256) void combine_out_proj(
    const u16* __restrict__ Opart, const float* __restrict__ Lsum,
    const u16* __restrict__ WoT, const float* __restrict__ bo,
    float* __restrict__ out) {
  const int row0 = blockIdx.x * 64;
  const int tid = threadIdx.x;
  const int wid = tid >> 6;
  const int lane = tid & 63;
  const int lg = lane >> 4, lr = lane & 15;
  const int m = row0 + wid * 16 + lr;

  float den = 0.f;
#pragma unroll
  for (int s = 0; s < NS; ++s) den += Lsum[(size_t)s * BLQ + m];
  const float inv = 1.f / den;

  float accO[4][8];
#pragma unroll
  for (int ks = 0; ks < 4; ++ks)
#pragma unroll
    for (int j = 0; j < 8; ++j) accO[ks][j] = 0.f;

#pragma unroll
  for (int s = 0; s < NS; ++s) {
    const u16* Op = Opart + ((size_t)s * BLQ + m) * 128;
#pragma unroll
    for (int ks = 0; ks < 4; ++ks) {
      const uint4v v =
          __builtin_nontemporal_load((const uint4v*)(Op + ks * 32 + lg * 8));
      accO[ks][0] += bf2f((u16)(v.x & 0xffff));
      accO[ks][1] += bf2f((u16)(v.x >> 16));
      accO[ks][2] += bf2f((u16)(v.y & 0xffff));
      accO[ks][3] += bf2f((u16)(v.y >> 16));
      accO[ks][4] += bf2f((u16)(v.z & 0xffff));
      accO[ks][5] += bf2f((u16)(v.z >> 16));
      accO[ks][6] += bf2f((u16)(v.w & 0xffff));
      accO[ks][7] += bf2f((u16)(v.w >> 16));
    }
  }

  bf16x8 ofrag[4];
#pragma unroll
  for (int ks = 0; ks < 4; ++ks) {
    Bf8Pack pk;
#pragma unroll
    for (int j = 0; j < 8; ++j) pk.u[j] = f2bf(accO[ks][j] * inv);
    ofrag[ks] = pk.v;
  }

#pragma unroll
  for (int dt = 0; dt < 8; ++dt) {
    f32x4 acc = (f32x4){0.f, 0.f, 0.f, 0.f};
#pragma unroll
    for (int ks = 0; ks < 4; ++ks) {
      const bf16x8 wf =
          *(const bf16x8*)(WoT + (size_t)(dt * 16 + lr) * DOUT + ks * 32 + lg * 8);
      acc = __builtin_amdgcn_mfma_f32_16x16x32_bf16(wf, ofrag[ks], acc, 0, 0, 0);
    }
    float4 o;
    o.x = acc[0] + bo[dt * 16 + lg * 4 + 0];
    o.y = acc[1] + bo[dt * 16 + lg * 4 + 1];
    o.z = acc[2] + bo[dt * 16 + lg * 4 + 2];
    o.w = acc[3] + bo[dt * 16 + lg * 4 + 3];
    *(float4*)(out + (size_t)m * DOUT + dt * 16 + lg * 4) = o;
  }
}

extern "C" void kernel_launch(void* const* d_in, const int* in_sizes, int n_in,
                              void* d_out, int out_size, void* d_ws,
                              size_t ws_size, hipStream_t stream) {
  const float* ligand = (const float*)d_in[0];
  const float* pocket = (const float*)d_in[1];
  const float* Wq = (const float*)d_in[2];
  const float* bq = (const float*)d_in[3];
  const float* Wk = (const float*)d_in[4];
  const float* bk = (const float*)d_in[5];
  const float* Wv = (const float*)d_in[6];
  const float* bv = (const float*)d_in[7];
  const float* Wo = (const float*)d_in[8];
  const float* bo = (const float*)d_in[9];
  float* out = (float*)d_out;

  const size_t MB = 1024 * 1024;
  char* ws = (char*)d_ws;
  u16* Qb = (u16*)(ws);                      // 4 MB
  u16* Kb = (u16*)(ws + 4 * MB);             // 4 MB
  u16* Vt = (u16*)(ws + 8 * MB);             // 4 MB (V^T)
  u16* Wt = (u16*)(ws + 12 * MB);            // 192 KB
  u16* WoT = Wt + 3 * DOUT * DIN;            // 32 KB
  const int ns = (ws_size >= 46 * MB) ? 8 : 4;
  u16* Opart = (u16*)(ws + 13 * MB);                            // ns*4 MB bf16
  float* Lsum = (float*)(ws + 13 * MB + (size_t)ns * 4 * MB);   // ns*64 KB

  wtrans_kernel<<<dim3(448), dim3(256), 0, stream>>>(Wq, Wk, Wv, Wo, Wt, WoT);

  dim3 g1(BLQ / 64, 3);
  qkv_proj_mfma<<<g1, dim3(256), 0, stream>>>(ligand, pocket, bq, bk, bv, Wt,
                                              Qb, Kb, Vt);

  dim3 g2(LQ / 128, B_SZ, ns);
  flash_attn_kernel<<<g2, dim3(256), 0, stream>>>(Qb, Kb, Vt, Opart, Lsum,
                                                  NT / ns);

  dim3 g3(BLQ / 64);
  if (ns == 8) {
    combine_out_proj<8><<<g3, dim3(256), 0, stream>>>(Opart, Lsum, WoT, bo, out);
  } else {
    combine_out_proj<4><<<g3, dim3(256), 0, stream>>>(Opart, Lsum, WoT, bo, out);
  }
}

// Round 14
// 117.306 us; speedup vs baseline: 1.5542x; 1.5542x over previous
//
#include <hip/hip_runtime.h>

#define B_SZ 4
#define LQ 4096
#define LKV 4096
#define DIN 256
#define DOUT 128
#define KVBLK 32
#define NT (LKV / KVBLK)
#define BLQ (B_SZ * LQ)
#define KTILE (KVBLK * 128)  // u16 elements per K or V tile (8 KB)

typedef unsigned short u16;
typedef __attribute__((ext_vector_type(8))) short bf16x8;
typedef __attribute__((ext_vector_type(4))) float f32x4;
typedef __attribute__((ext_vector_type(16))) float f32x16;

union Bf8Pack {
  u16 u[8];
  bf16x8 v;
};
union U16x4Pack {
  u16 u[4];
  uint2 v;
};
union PFrag {
  unsigned u[4];
  bf16x8 v;
};

__device__ __forceinline__ u16 f2bf(float x) {
  unsigned u = __float_as_uint(x);
  u += 0x7fffu + ((u >> 16) & 1u);
  return (u16)(u >> 16);
}

__device__ __forceinline__ float bf2f(u16 x) {
  return __uint_as_float(((unsigned)x) << 16);
}

__device__ __forceinline__ unsigned cvt_pk_bf16(float lo, float hi) {
  unsigned r;
  asm("v_cvt_pk_bf16_f32 %0, %1, %2" : "=v"(r) : "v"(lo), "v"(hi));
  return r;
}

__device__ __forceinline__ void gload_lds16(const u16* g, u16* l) {
  __builtin_amdgcn_global_load_lds(
      (__attribute__((address_space(1))) unsigned int*)g,
      (__attribute__((address_space(3))) unsigned int*)l, 16, 0, 0);
}

// ---------- weight transpose + bf16 convert: Wt[3][128][256], WoT[128][128] ----------
__global__ __launch_bounds__(256) void wtrans_kernel(
    const float* __restrict__ Wq, const float* __restrict__ Wk,
    const float* __restrict__ Wv, const float* __restrict__ Wo,
    u16* __restrict__ Wt, u16* __restrict__ WoT) {
  const int gid = blockIdx.x * 256 + threadIdx.x;
  if (gid < 3 * DOUT * DIN) {
    const int which = gid / (DOUT * DIN);
    const int r = gid % (DOUT * DIN);
    const int n = r >> 8;
    const int k = r & 255;
    const float* W = (which == 0) ? Wq : (which == 1) ? Wk : Wv;
    Wt[gid] = f2bf(W[k * DOUT + n]);
  } else {
    const int r = gid - 3 * DOUT * DIN;
    if (r < DOUT * DOUT) {
      const int n = r >> 7;
      const int k = r & 127;
      WoT[r] = f2bf(Wo[k * DOUT + n]);
    }
  }
}

// ---------- QKV projection via MFMA (r8 3-way form) ----------
__global__ __launch_bounds__(256) void qkv_proj_mfma(
    const float* __restrict__ ligand, const float* __restrict__ pocket,
    const float* __restrict__ bq, const float* __restrict__ bk,
    const float* __restrict__ bv, const u16* __restrict__ Wt,
    u16* __restrict__ Qb, u16* __restrict__ Kb, u16* __restrict__ Vt) {
  const int which = blockIdx.y;
  const int row0 = blockIdx.x * 64;
  const int tid = threadIdx.x;
  const int wid = tid >> 6;
  const int lane = tid & 63;
  const int lg = lane >> 4, lr = lane & 15;
  const float* __restrict__ src = (which == 0) ? ligand : pocket;
  const int m = row0 + wid * 16 + lr;

  bf16x8 sfrag[8];
#pragma unroll
  for (int ks = 0; ks < 8; ++ks) {
    const float* p = src + (size_t)m * DIN + ks * 32 + lg * 8;
    const float4 a = *(const float4*)p;
    const float4 b = *(const float4*)(p + 4);
    Bf8Pack pk;
    pk.u[0] = f2bf(a.x); pk.u[1] = f2bf(a.y); pk.u[2] = f2bf(a.z); pk.u[3] = f2bf(a.w);
    pk.u[4] = f2bf(b.x); pk.u[5] = f2bf(b.y); pk.u[6] = f2bf(b.z); pk.u[7] = f2bf(b.w);
    sfrag[ks] = pk.v;
  }

  if (which < 2) {
    const float* __restrict__ bias = (which == 0) ? bq : bk;
    u16* __restrict__ dst = (which == 0) ? Qb : Kb;
    const u16* __restrict__ Wtw = Wt + (size_t)which * DOUT * DIN;
    // Q pre-scaled by 1/sqrt(128) * log2(e): flash uses exp2 with fixed m=0.
    const float qscale = (float)(0.08838834764831845 * 1.4426950408889634);
#pragma unroll
    for (int dt = 0; dt < 8; ++dt) {
      f32x4 acc = (f32x4){0.f, 0.f, 0.f, 0.f};
#pragma unroll
      for (int ks = 0; ks < 8; ++ks) {
        const bf16x8 wf =
            *(const bf16x8*)(Wtw + (size_t)(dt * 16 + lr) * DIN + ks * 32 + lg * 8);
        acc = __builtin_amdgcn_mfma_f32_16x16x32_bf16(wf, sfrag[ks], acc, 0, 0, 0);
      }
      U16x4Pack st;
#pragma unroll
      for (int j = 0; j < 4; ++j) {
        float v = acc[j] + bias[dt * 16 + lg * 4 + j];
        if (which == 0) v *= qscale;
        st.u[j] = f2bf(v);
      }
      *(uint2*)(dst + (size_t)m * DOUT + dt * 16 + lg * 4) = st.v;
    }
  } else {
    // V: C[m][d] orientation, transposed output V^T[d][kv]
    const u16* __restrict__ Wtv = Wt + 2 * DOUT * DIN;
    const int batch = row0 >> 12;
    const int kvbase = (row0 & 4095) + wid * 16 + lg * 4;
#pragma unroll
    for (int dt = 0; dt < 8; ++dt) {
      f32x4 acc = (f32x4){0.f, 0.f, 0.f, 0.f};
#pragma unroll
      for (int ks = 0; ks < 8; ++ks) {
        const bf16x8 wf =
            *(const bf16x8*)(Wtv + (size_t)(dt * 16 + lr) * DIN + ks * 32 + lg * 8);
        acc = __builtin_amdgcn_mfma_f32_16x16x32_bf16(sfrag[ks], wf, acc, 0, 0, 0);
      }
      const int d = dt * 16 + lr;
      const float b = bv[d];
      U16x4Pack st;
#pragma unroll
      for (int j = 0; j < 4; ++j) st.u[j] = f2bf(acc[j] + b);
      *(uint2*)(Vt + ((size_t)batch * DOUT + d) * LKV + kvbase) = st.v;
    }
  }
}

// ---------------- Flash attention: r8 byte-exact core (32x32x16, P in-register,
// double-buffer, one __syncthreads/iter, shfl_xor row-sum, plain stores).
__global__ __launch_bounds__(256, 4) void flash_attn_kernel(
    const u16* __restrict__ Qb, const u16* __restrict__ Kb,
    const u16* __restrict__ Vt, u16* __restrict__ Opart,
    float* __restrict__ Lsum, int niter) {
  __shared__ __align__(16) u16 Ks[2 * KTILE];
  __shared__ __align__(16) u16 Vs[2 * KTILE];

  const int batch = blockIdx.y;
  const int split = blockIdx.z;
  const int q0 = blockIdx.x * 128;
  const int tid = threadIdx.x;
  const int wid = tid >> 6;
  const int lane = tid & 63;
  const int ql = lane & 31;
  const int h = lane >> 5;
  const int t0 = split * niter;

  // staging source offsets (u16 elements): 512 chunks/tile, 2 per thread
  int koff[2], voff[2];
#pragma unroll
  for (int i = 0; i < 2; ++i) {
    const int c = i * 256 + tid;
    koff[i] = (c & 31) * 128 + (c >> 6) * 16 + ((c >> 5) & 1) * 8;
    voff[i] = ((c >> 7) * 32 + (c & 31)) * LKV + (((c >> 6) & 1) << 4) +
              (((c >> 5) & 1) << 3);
  }
  const u16* KbB = Kb + (size_t)batch * LKV * 128 + (size_t)t0 * KTILE;
  const u16* VtB = Vt + (size_t)batch * 128 * LKV + t0 * KVBLK;

#define STAGEKV(buf, t)                                                      \
  {                                                                          \
    _Pragma("unroll") for (int i = 0; i < 2; ++i)                            \
        gload_lds16(KbB + (t) * KTILE + koff[i],                             \
                    Ks + (buf) * KTILE + (i * 256 + tid) * 8);               \
    _Pragma("unroll") for (int i = 0; i < 2; ++i)                            \
        gload_lds16(VtB + (t) * KVBLK + voff[i],                             \
                    Vs + (buf) * KTILE + (i * 256 + tid) * 8);               \
  }

  // Q fragments: lane holds Q[q0+wid*32+ql][ks*16 + h*8 ..+8], ks=0..7
  const u16* Qw = Qb + ((size_t)batch * LQ + q0 + wid * 32) * 128;
  bf16x8 qf[8];
#pragma unroll
  for (int ks = 0; ks < 8; ++ks)
    qf[ks] = *(const bf16x8*)(Qw + (size_t)ql * 128 + ks * 16 + h * 8);

  f32x16 oacc[4];
#pragma unroll
  for (int dt = 0; dt < 4; ++dt)
#pragma unroll
    for (int r = 0; r < 16; ++r) oacc[dt][r] = 0.f;
  float l_run = 0.f;

  STAGEKV(0, 0);
  __syncthreads();

  int cur = 0;
  for (int t = 0; t < niter; ++t) {
    if (t + 1 < niter) STAGEKV(cur ^ 1, t + 1);

    const u16* kread = Ks + cur * KTILE + lane * 8;
    const u16* vread = Vs + cur * KTILE + lane * 8;

    // S = K · Q^T  (D[kv][q], col q = lane&31)
    f32x16 sacc;
#pragma unroll
    for (int r = 0; r < 16; ++r) sacc[r] = 0.f;
#pragma unroll
    for (int ks = 0; ks < 8; ++ks) {
      const bf16x8 kf = *(const bf16x8*)(kread + ks * 512);
      sacc = __builtin_amdgcn_mfma_f32_32x32x16_bf16(kf, qf[ks], sacc, 0, 0, 0);
    }

    // fixed-m softmax (log2 domain): p = exp2(s); pairwise tree sum
    float p[16];
#pragma unroll
    for (int r = 0; r < 16; ++r) p[r] = exp2f(sacc[r]);
    float rs = (((p[0] + p[1]) + (p[2] + p[3])) + ((p[4] + p[5]) + (p[6] + p[7]))) +
               (((p[8] + p[9]) + (p[10] + p[11])) + ((p[12] + p[13]) + (p[14] + p[15])));
    rs += __shfl_xor(rs, 32, 64);
    l_run += rs;

    // pack P to bf16 pairs, redistribute halves via permlane32_swap
    unsigned w0 = cvt_pk_bf16(p[0], p[1]);
    unsigned w1 = cvt_pk_bf16(p[2], p[3]);
    unsigned w2 = cvt_pk_bf16(p[4], p[5]);
    unsigned w3 = cvt_pk_bf16(p[6], p[7]);
    unsigned w4 = cvt_pk_bf16(p[8], p[9]);
    unsigned w5 = cvt_pk_bf16(p[10], p[11]);
    unsigned w6 = cvt_pk_bf16(p[12], p[13]);
    unsigned w7 = cvt_pk_bf16(p[14], p[15]);
    asm("v_permlane32_swap_b32 %0, %1" : "+v"(w0), "+v"(w2));
    asm("v_permlane32_swap_b32 %0, %1" : "+v"(w1), "+v"(w3));
    asm("v_permlane32_swap_b32 %0, %1" : "+v"(w4), "+v"(w6));
    asm("v_permlane32_swap_b32 %0, %1" : "+v"(w5), "+v"(w7));
    PFrag pa0, pa1;
    pa0.u[0] = w0; pa0.u[1] = w1; pa0.u[2] = w2; pa0.u[3] = w3;  // kv 0..15
    pa1.u[0] = w4; pa1.u[1] = w5; pa1.u[2] = w6; pa1.u[3] = w7;  // kv 16..31

    // O^T += V^T · P^T
#pragma unroll
    for (int dt = 0; dt < 4; ++dt) {
      const bf16x8 vf0 = *(const bf16x8*)(vread + (dt * 2 + 0) * 512);
      oacc[dt] = __builtin_amdgcn_mfma_f32_32x32x16_bf16(vf0, pa0.v, oacc[dt], 0, 0, 0);
      const bf16x8 vf1 = *(const bf16x8*)(vread + (dt * 2 + 1) * 512);
      oacc[dt] = __builtin_amdgcn_mfma_f32_32x32x16_bf16(vf1, pa1.v, oacc[dt], 0, 0, 0);
    }

    __syncthreads();
    cur ^= 1;
  }

  // write bf16 unnormalized partials + row sums (m = 0 global)
  const size_t rowbase = (size_t)split * BLQ + (size_t)batch * LQ + q0 + wid * 32;
  u16* Op = Opart + (rowbase + ql) * 128;
#pragma unroll
  for (int dt = 0; dt < 4; ++dt)
#pragma unroll
    for (int g2 = 0; g2 < 4; ++g2) {
      uint2 st;
      st.x = cvt_pk_bf16(oacc[dt][g2 * 4 + 0], oacc[dt][g2 * 4 + 1]);
      st.y = cvt_pk_bf16(oacc[dt][g2 * 4 + 2], oacc[dt][g2 * 4 + 3]);
      *(uint2*)(Op + dt * 32 + g2 * 8 + h * 4) = st;
    }
  if (lane < 32) Lsum[rowbase + lane] = l_run;
#undef STAGEKV
}

// ---------- combine KV-splits (linear, m=0) + output projection via MFMA ----------
template <int NS>
__global__ __launch_bounds__(256) void combine_out_proj(
    const u16* __restrict__ Opart, const float* __restrict__ Lsum,
    const u16* __restrict__ WoT, const float* __restrict__ bo,
    float* __restrict__ out) {
  const int row0 = blockIdx.x * 64;
  const int tid = threadIdx.x;
  const int wid = tid >> 6;
  const int lane = tid & 63;
  const int lg = lane >> 4, lr = lane & 15;
  const int m = row0 + wid * 16 + lr;

  float den = 0.f;
#pragma unroll
  for (int s = 0; s < NS; ++s) den += Lsum[(size_t)s * BLQ + m];
  const float inv = 1.f / den;

  float accO[4][8];
#pragma unroll
  for (int ks = 0; ks < 4; ++ks)
#pragma unroll
    for (int j = 0; j < 8; ++j) accO[ks][j] = 0.f;

#pragma unroll
  for (int s = 0; s < NS; ++s) {
    const u16* Op = Opart + ((size_t)s * BLQ + m) * 128;
#pragma unroll
    for (int ks = 0; ks < 4; ++ks) {
      const uint4 v = *(const uint4*)(Op + ks * 32 + lg * 8);
      accO[ks][0] += bf2f((u16)(v.x & 0xffff));
      accO[ks][1] += bf2f((u16)(v.x >> 16));
      accO[ks][2] += bf2f((u16)(v.y & 0xffff));
      accO[ks][3] += bf2f((u16)(v.y >> 16));
      accO[ks][4] += bf2f((u16)(v.z & 0xffff));
      accO[ks][5] += bf2f((u16)(v.z >> 16));
      accO[ks][6] += bf2f((u16)(v.w & 0xffff));
      accO[ks][7] += bf2f((u16)(v.w >> 16));
    }
  }

  bf16x8 ofrag[4];
#pragma unroll
  for (int ks = 0; ks < 4; ++ks) {
    Bf8Pack pk;
#pragma unroll
    for (int j = 0; j < 8; ++j) pk.u[j] = f2bf(accO[ks][j] * inv);
    ofrag[ks] = pk.v;
  }

#pragma unroll
  for (int dt = 0; dt < 8; ++dt) {
    f32x4 acc = (f32x4){0.f, 0.f, 0.f, 0.f};
#pragma unroll
    for (int ks = 0; ks < 4; ++ks) {
      const bf16x8 wf =
          *(const bf16x8*)(WoT + (size_t)(dt * 16 + lr) * DOUT + ks * 32 + lg * 8);
      acc = __builtin_amdgcn_mfma_f32_16x16x32_bf16(wf, ofrag[ks], acc, 0, 0, 0);
    }
    float4 o;
    o.x = acc[0] + bo[dt * 16 + lg * 4 + 0];
    o.y = acc[1] + bo[dt * 16 + lg * 4 + 1];
    o.z = acc[2] + bo[dt * 16 + lg * 4 + 2];
    o.w = acc[3] + bo[dt * 16 + lg * 4 + 3];
    *(float4*)(out + (size_t)m * DOUT + dt * 16 + lg * 4) = o;
  }
}

extern "C" void kernel_launch(void* const* d_in, const int* in_sizes, int n_in,
                              void* d_out, int out_size, void* d_ws,
                              size_t ws_size, hipStream_t stream) {
  const float* ligand = (const float*)d_in[0];
  const float* pocket = (const float*)d_in[1];
  const float* Wq = (const float*)d_in[2];
  const float* bq = (const float*)d_in[3];
  const float* Wk = (const float*)d_in[4];
  const float* bk = (const float*)d_in[5];
  const float* Wv = (const float*)d_in[6];
  const float* bv = (const float*)d_in[7];
  const float* Wo = (const float*)d_in[8];
  const float* bo = (const float*)d_in[9];
  float* out = (float*)d_out;

  const size_t MB = 1024 * 1024;
  char* ws = (char*)d_ws;
  u16* Qb = (u16*)(ws);                      // 4 MB
  u16* Kb = (u16*)(ws + 4 * MB);             // 4 MB
  u16* Vt = (u16*)(ws + 8 * MB);             // 4 MB (V^T)
  u16* Wt = (u16*)(ws + 12 * MB);            // 192 KB
  u16* WoT = Wt + 3 * DOUT * DIN;            // 32 KB
  const int ns = (ws_size >= 46 * MB) ? 8 : 4;
  u16* Opart = (u16*)(ws + 13 * MB);                            // ns*4 MB bf16
  float* Lsum = (float*)(ws + 13 * MB + (size_t)ns * 4 * MB);   // ns*64 KB

  wtrans_kernel<<<dim3(448), dim3(256), 0, stream>>>(Wq, Wk, Wv, Wo, Wt, WoT);

  dim3 g1(BLQ / 64, 3);
  qkv_proj_mfma<<<g1, dim3(256), 0, stream>>>(ligand, pocket, bq, bk, bv, Wt,
                                              Qb, Kb, Vt);

  dim3 g2(LQ / 128, B_SZ, ns);
  flash_attn_kernel<<<g2, dim3(256), 0, stream>>>(Qb, Kb, Vt, Opart, Lsum,
                                                  NT / ns);

  dim3 g3(BLQ / 64);
  if (ns == 8) {
    combine_out_proj<8><<<g3, dim3(256), 0, stream>>>(Opart, Lsum, WoT, bo, out);
  } else {
    combine_out_proj<4><<<g3, dim3(256), 0, stream>>>(Opart, Lsum, WoT, bo, out);
  }
}

// Round 15
// 99.816 us; speedup vs baseline: 1.8265x; 1.1752x over previous
//
#include <hip/hip_runtime.h>

#define B_SZ 4
#define LQ 4096
#define LKV 4096
#define DIN 256
#define DOUT 128
#define KVBLK 32
#define NT (LKV / KVBLK)
#define BLQ (B_SZ * LQ)
#define KTILE (KVBLK * 128)  // u16 elements per K or V tile (8 KB)

typedef unsigned short u16;
typedef __attribute__((ext_vector_type(8))) short bf16x8;
typedef __attribute__((ext_vector_type(4))) float f32x4;
typedef __attribute__((ext_vector_type(16))) float f32x16;

union Bf8Pack {
  u16 u[8];
  bf16x8 v;
};
union U16x4Pack {
  u16 u[4];
  uint2 v;
};
union PFrag {
  unsigned u[4];
  bf16x8 v;
};

__device__ __forceinline__ u16 f2bf(float x) {
  unsigned u = __float_as_uint(x);
  u += 0x7fffu + ((u >> 16) & 1u);
  return (u16)(u >> 16);
}

__device__ __forceinline__ float bf2f(u16 x) {
  return __uint_as_float(((unsigned)x) << 16);
}

__device__ __forceinline__ unsigned cvt_pk_bf16(float lo, float hi) {
  unsigned r;
  asm("v_cvt_pk_bf16_f32 %0, %1, %2" : "=v"(r) : "v"(lo), "v"(hi));
  return r;
}

__device__ __forceinline__ void gload_lds16(const u16* g, u16* l) {
  __builtin_amdgcn_global_load_lds(
      (__attribute__((address_space(1))) unsigned int*)g,
      (__attribute__((address_space(3))) unsigned int*)l, 16, 0, 0);
}

// ---------- weight transpose + bf16 convert: Wt[3][128][256], WoT[128][128] ----------
__global__ __launch_bounds__(256) void wtrans_kernel(
    const float* __restrict__ Wq, const float* __restrict__ Wk,
    const float* __restrict__ Wv, const float* __restrict__ Wo,
    u16* __restrict__ Wt, u16* __restrict__ WoT) {
  const int gid = blockIdx.x * 256 + threadIdx.x;
  if (gid < 3 * DOUT * DIN) {
    const int which = gid / (DOUT * DIN);
    const int r = gid % (DOUT * DIN);
    const int n = r >> 8;
    const int k = r & 255;
    const float* W = (which == 0) ? Wq : (which == 1) ? Wk : Wv;
    Wt[gid] = f2bf(W[k * DOUT + n]);
  } else {
    const int r = gid - 3 * DOUT * DIN;
    if (r < DOUT * DOUT) {
      const int n = r >> 7;
      const int k = r & 127;
      WoT[r] = f2bf(Wo[k * DOUT + n]);
    }
  }
}

// ---------- QKV projection via MFMA, W staged in LDS (fragment-ordered) ----------
// grid (BLQ/64, 3), block 256. Fragment f = dt*8+ks lives at Wlds[f*512 + lane*8]:
// lane (lg,lr) holds W^T[dt*16+lr][ks*32+lg*8 ..+8]. Reads are lane*16B -> 0 conflicts.
__global__ __launch_bounds__(256) void qkv_proj_mfma(
    const float* __restrict__ ligand, const float* __restrict__ pocket,
    const float* __restrict__ bq, const float* __restrict__ bk,
    const float* __restrict__ bv, const u16* __restrict__ Wt,
    u16* __restrict__ Qb, u16* __restrict__ Kb, u16* __restrict__ Vt) {
  __shared__ __align__(16) u16 Wlds[DOUT * DIN];  // 64 KB
  const int which = blockIdx.y;
  const int row0 = blockIdx.x * 64;
  const int tid = threadIdx.x;
  const int wid = tid >> 6;
  const int lane = tid & 63;
  const int lg = lane >> 4, lr = lane & 15;

  // stage W in fragment order: 4096 x 16B chunks, 16 per thread
  const u16* __restrict__ Wtw = Wt + (size_t)which * DOUT * DIN;
#pragma unroll
  for (int i = 0; i < 16; ++i) {
    const int c = i * 256 + tid;
    const int f = c >> 6;  // dt = f>>3, ks = f&7
    const int l = c & 63;
    const int src = ((f >> 3) * 16 + (l & 15)) * DIN + (f & 7) * 32 + (l >> 4) * 8;
    gload_lds16(Wtw + src, Wlds + (size_t)c * 8);
  }

  const float* __restrict__ srcp = (which == 0) ? ligand : pocket;
  const int m = row0 + wid * 16 + lr;

  bf16x8 sfrag[8];
#pragma unroll
  for (int ks = 0; ks < 8; ++ks) {
    const float* p = srcp + (size_t)m * DIN + ks * 32 + lg * 8;
    const float4 a = *(const float4*)p;
    const float4 b = *(const float4*)(p + 4);
    Bf8Pack pk;
    pk.u[0] = f2bf(a.x); pk.u[1] = f2bf(a.y); pk.u[2] = f2bf(a.z); pk.u[3] = f2bf(a.w);
    pk.u[4] = f2bf(b.x); pk.u[5] = f2bf(b.y); pk.u[6] = f2bf(b.z); pk.u[7] = f2bf(b.w);
    sfrag[ks] = pk.v;
  }

  __syncthreads();  // drains staging (and sfrag loads)
  const u16* wread = Wlds + lane * 8;

  if (which < 2) {
    const float* __restrict__ bias = (which == 0) ? bq : bk;
    u16* __restrict__ dst = (which == 0) ? Qb : Kb;
    // Q pre-scaled by 1/sqrt(128) * log2(e): flash uses exp2 with fixed m=0.
    const float qscale = (float)(0.08838834764831845 * 1.4426950408889634);
#pragma unroll
    for (int dt = 0; dt < 8; ++dt) {
      f32x4 acc = (f32x4){0.f, 0.f, 0.f, 0.f};
#pragma unroll
      for (int ks = 0; ks < 8; ++ks) {
        const bf16x8 wf = *(const bf16x8*)(wread + (dt * 8 + ks) * 512);
        acc = __builtin_amdgcn_mfma_f32_16x16x32_bf16(wf, sfrag[ks], acc, 0, 0, 0);
      }
      U16x4Pack st;
#pragma unroll
      for (int j = 0; j < 4; ++j) {
        float v = acc[j] + bias[dt * 16 + lg * 4 + j];
        if (which == 0) v *= qscale;
        st.u[j] = f2bf(v);
      }
      *(uint2*)(dst + (size_t)m * DOUT + dt * 16 + lg * 4) = st.v;
    }
  } else {
    // V: C[m][d] orientation, transposed output V^T[d][kv]
    const int batch = row0 >> 12;
    const int kvbase = (row0 & 4095) + wid * 16 + lg * 4;
#pragma unroll
    for (int dt = 0; dt < 8; ++dt) {
      f32x4 acc = (f32x4){0.f, 0.f, 0.f, 0.f};
#pragma unroll
      for (int ks = 0; ks < 8; ++ks) {
        const bf16x8 wf = *(const bf16x8*)(wread + (dt * 8 + ks) * 512);
        acc = __builtin_amdgcn_mfma_f32_16x16x32_bf16(sfrag[ks], wf, acc, 0, 0, 0);
      }
      const int d = dt * 16 + lr;
      const float b = bv[d];
      U16x4Pack st;
#pragma unroll
      for (int j = 0; j < 4; ++j) st.u[j] = f2bf(acc[j] + b);
      *(uint2*)(Vt + ((size_t)batch * DOUT + d) * LKV + kvbase) = st.v;
    }
  }
}

// ---------------- Flash attention: r8 byte-exact core (32x32x16, P in-register,
// double-buffer, one __syncthreads/iter, shfl_xor row-sum, plain stores).
__global__ __launch_bounds__(256, 4) void flash_attn_kernel(
    const u16* __restrict__ Qb, const u16* __restrict__ Kb,
    const u16* __restrict__ Vt, u16* __restrict__ Opart,
    float* __restrict__ Lsum, int niter) {
  __shared__ __align__(16) u16 Ks[2 * KTILE];
  __shared__ __align__(16) u16 Vs[2 * KTILE];

  const int batch = blockIdx.y;
  const int split = blockIdx.z;
  const int q0 = blockIdx.x * 128;
  const int tid = threadIdx.x;
  const int wid = tid >> 6;
  const int lane = tid & 63;
  const int ql = lane & 31;
  const int h = lane >> 5;
  const int t0 = split * niter;

  // staging source offsets (u16 elements): 512 chunks/tile, 2 per thread
  int koff[2], voff[2];
#pragma unroll
  for (int i = 0; i < 2; ++i) {
    const int c = i * 256 + tid;
    koff[i] = (c & 31) * 128 + (c >> 6) * 16 + ((c >> 5) & 1) * 8;
    voff[i] = ((c >> 7) * 32 + (c & 31)) * LKV + (((c >> 6) & 1) << 4) +
              (((c >> 5) & 1) << 3);
  }
  const u16* KbB = Kb + (size_t)batch * LKV * 128 + (size_t)t0 * KTILE;
  const u16* VtB = Vt + (size_t)batch * 128 * LKV + t0 * KVBLK;

#define STAGEKV(buf, t)                                                      \
  {                                                                          \
    _Pragma("unroll") for (int i = 0; i < 2; ++i)                            \
        gload_lds16(KbB + (t) * KTILE + koff[i],                             \
                    Ks + (buf) * KTILE + (i * 256 + tid) * 8);               \
    _Pragma("unroll") for (int i = 0; i < 2; ++i)                            \
        gload_lds16(VtB + (t) * KVBLK + voff[i],                             \
                    Vs + (buf) * KTILE + (i * 256 + tid) * 8);               \
  }

  // Q fragments: lane holds Q[q0+wid*32+ql][ks*16 + h*8 ..+8], ks=0..7
  const u16* Qw = Qb + ((size_t)batch * LQ + q0 + wid * 32) * 128;
  bf16x8 qf[8];
#pragma unroll
  for (int ks = 0; ks < 8; ++ks)
    qf[ks] = *(const bf16x8*)(Qw + (size_t)ql * 128 + ks * 16 + h * 8);

  f32x16 oacc[4];
#pragma unroll
  for (int dt = 0; dt < 4; ++dt)
#pragma unroll
    for (int r = 0; r < 16; ++r) oacc[dt][r] = 0.f;
  float l_run = 0.f;

  STAGEKV(0, 0);
  __syncthreads();

  int cur = 0;
  for (int t = 0; t < niter; ++t) {
    if (t + 1 < niter) STAGEKV(cur ^ 1, t + 1);

    const u16* kread = Ks + cur * KTILE + lane * 8;
    const u16* vread = Vs + cur * KTILE + lane * 8;

    // S = K · Q^T  (D[kv][q], col q = lane&31)
    f32x16 sacc;
#pragma unroll
    for (int r = 0; r < 16; ++r) sacc[r] = 0.f;
#pragma unroll
    for (int ks = 0; ks < 8; ++ks) {
      const bf16x8 kf = *(const bf16x8*)(kread + ks * 512);
      sacc = __builtin_amdgcn_mfma_f32_32x32x16_bf16(kf, qf[ks], sacc, 0, 0, 0);
    }

    // fixed-m softmax (log2 domain): p = exp2(s); pairwise tree sum
    float p[16];
#pragma unroll
    for (int r = 0; r < 16; ++r) p[r] = exp2f(sacc[r]);
    float rs = (((p[0] + p[1]) + (p[2] + p[3])) + ((p[4] + p[5]) + (p[6] + p[7]))) +
               (((p[8] + p[9]) + (p[10] + p[11])) + ((p[12] + p[13]) + (p[14] + p[15])));
    rs += __shfl_xor(rs, 32, 64);
    l_run += rs;

    // pack P to bf16 pairs, redistribute halves via permlane32_swap
    unsigned w0 = cvt_pk_bf16(p[0], p[1]);
    unsigned w1 = cvt_pk_bf16(p[2], p[3]);
    unsigned w2 = cvt_pk_bf16(p[4], p[5]);
    unsigned w3 = cvt_pk_bf16(p[6], p[7]);
    unsigned w4 = cvt_pk_bf16(p[8], p[9]);
    unsigned w5 = cvt_pk_bf16(p[10], p[11]);
    unsigned w6 = cvt_pk_bf16(p[12], p[13]);
    unsigned w7 = cvt_pk_bf16(p[14], p[15]);
    asm("v_permlane32_swap_b32 %0, %1" : "+v"(w0), "+v"(w2));
    asm("v_permlane32_swap_b32 %0, %1" : "+v"(w1), "+v"(w3));
    asm("v_permlane32_swap_b32 %0, %1" : "+v"(w4), "+v"(w6));
    asm("v_permlane32_swap_b32 %0, %1" : "+v"(w5), "+v"(w7));
    PFrag pa0, pa1;
    pa0.u[0] = w0; pa0.u[1] = w1; pa0.u[2] = w2; pa0.u[3] = w3;  // kv 0..15
    pa1.u[0] = w4; pa1.u[1] = w5; pa1.u[2] = w6; pa1.u[3] = w7;  // kv 16..31

    // O^T += V^T · P^T
#pragma unroll
    for (int dt = 0; dt < 4; ++dt) {
      const bf16x8 vf0 = *(const bf16x8*)(vread + (dt * 2 + 0) * 512);
      oacc[dt] = __builtin_amdgcn_mfma_f32_32x32x16_bf16(vf0, pa0.v, oacc[dt], 0, 0, 0);
      const bf16x8 vf1 = *(const bf16x8*)(vread + (dt * 2 + 1) * 512);
      oacc[dt] = __builtin_amdgcn_mfma_f32_32x32x16_bf16(vf1, pa1.v, oacc[dt], 0, 0, 0);
    }

    __syncthreads();
    cur ^= 1;
  }

  // write bf16 unnormalized partials + row sums (m = 0 global)
  const size_t rowbase = (size_t)split * BLQ + (size_t)batch * LQ + q0 + wid * 32;
  u16* Op = Opart + (rowbase + ql) * 128;
#pragma unroll
  for (int dt = 0; dt < 4; ++dt)
#pragma unroll
    for (int g2 = 0; g2 < 4; ++g2) {
      uint2 st;
      st.x = cvt_pk_bf16(oacc[dt][g2 * 4 + 0], oacc[dt][g2 * 4 + 1]);
      st.y = cvt_pk_bf16(oacc[dt][g2 * 4 + 2], oacc[dt][g2 * 4 + 3]);
      *(uint2*)(Op + dt * 32 + g2 * 8 + h * 4) = st;
    }
  if (lane < 32) Lsum[rowbase + lane] = l_run;
#undef STAGEKV
}

// ---------- combine KV-splits (linear, m=0) + output projection via MFMA ----------
template <int NS>
__global__ __launch_bounds__(256) void combine_out_proj(
    const u16* __restrict__ Opart, const float* __restrict__ Lsum,
    const u16* __restrict__ WoT, const float* __restrict__ bo,
    float* __restrict__ out) {
  const int row0 = blockIdx.x * 64;
  const int tid = threadIdx.x;
  const int wid = tid >> 6;
  const int lane = tid & 63;
  const int lg = lane >> 4, lr = lane & 15;
  const int m = row0 + wid * 16 + lr;

  float den = 0.f;
#pragma unroll
  for (int s = 0; s < NS; ++s) den += Lsum[(size_t)s * BLQ + m];
  const float inv = 1.f / den;

  float accO[4][8];
#pragma unroll
  for (int ks = 0; ks < 4; ++ks)
#pragma unroll
    for (int j = 0; j < 8; ++j) accO[ks][j] = 0.f;

#pragma unroll
  for (int s = 0; s < NS; ++s) {
    const u16* Op = Opart + ((size_t)s * BLQ + m) * 128;
#pragma unroll
    for (int ks = 0; ks < 4; ++ks) {
      const uint4 v = *(const uint4*)(Op + ks * 32 + lg * 8);
      accO[ks][0] += bf2f((u16)(v.x & 0xffff));
      accO[ks][1] += bf2f((u16)(v.x >> 16));
      accO[ks][2] += bf2f((u16)(v.y & 0xffff));
      accO[ks][3] += bf2f((u16)(v.y >> 16));
      accO[ks][4] += bf2f((u16)(v.z & 0xffff));
      accO[ks][5] += bf2f((u16)(v.z >> 16));
      accO[ks][6] += bf2f((u16)(v.w & 0xffff));
      accO[ks][7] += bf2f((u16)(v.w >> 16));
    }
  }

  bf16x8 ofrag[4];
#pragma unroll
  for (int ks = 0; ks < 4; ++ks) {
    Bf8Pack pk;
#pragma unroll
    for (int j = 0; j < 8; ++j) pk.u[j] = f2bf(accO[ks][j] * inv);
    ofrag[ks] = pk.v;
  }

#pragma unroll
  for (int dt = 0; dt < 8; ++dt) {
    f32x4 acc = (f32x4){0.f, 0.f, 0.f, 0.f};
#pragma unroll
    for (int ks = 0; ks < 4; ++ks) {
      const bf16x8 wf =
          *(const bf16x8*)(WoT + (size_t)(dt * 16 + lr) * DOUT + ks * 32 + lg * 8);
      acc = __builtin_amdgcn_mfma_f32_16x16x32_bf16(wf, ofrag[ks], acc, 0, 0, 0);
    }
    float4 o;
    o.x = acc[0] + bo[dt * 16 + lg * 4 + 0];
    o.y = acc[1] + bo[dt * 16 + lg * 4 + 1];
    o.z = acc[2] + bo[dt * 16 + lg * 4 + 2];
    o.w = acc[3] + bo[dt * 16 + lg * 4 + 3];
    *(float4*)(out + (size_t)m * DOUT + dt * 16 + lg * 4) = o;
  }
}

extern "C" void kernel_launch(void* const* d_in, const int* in_sizes, int n_in,
                              void* d_out, int out_size, void* d_ws,
                              size_t ws_size, hipStream_t stream) {
  const float* ligand = (const float*)d_in[0];
  const float* pocket = (const float*)d_in[1];
  const float* Wq = (const float*)d_in[2];
  const float* bq = (const float*)d_in[3];
  const float* Wk = (const float*)d_in[4];
  const float* bk = (const float*)d_in[5];
  const float* Wv = (const float*)d_in[6];
  const float* bv = (const float*)d_in[7];
  const float* Wo = (const float*)d_in[8];
  const float* bo = (const float*)d_in[9];
  float* out = (float*)d_out;

  const size_t MB = 1024 * 1024;
  char* ws = (char*)d_ws;
  u16* Qb = (u16*)(ws);                      // 4 MB
  u16* Kb = (u16*)(ws + 4 * MB);             // 4 MB
  u16* Vt = (u16*)(ws + 8 * MB);             // 4 MB (V^T)
  u16* Wt = (u16*)(ws + 12 * MB);            // 192 KB
  u16* WoT = Wt + 3 * DOUT * DIN;            // 32 KB
  const int ns = (ws_size >= 46 * MB) ? 8 : 4;
  u16* Opart = (u16*)(ws + 13 * MB);                            // ns*4 MB bf16
  float* Lsum = (float*)(ws + 13 * MB + (size_t)ns * 4 * MB);   // ns*64 KB

  wtrans_kernel<<<dim3(448), dim3(256), 0, stream>>>(Wq, Wk, Wv, Wo, Wt, WoT);

  dim3 g1(BLQ / 64, 3);
  qkv_proj_mfma<<<g1, dim3(256), 0, stream>>>(ligand, pocket, bq, bk, bv, Wt,
                                              Qb, Kb, Vt);

  dim3 g2(LQ / 128, B_SZ, ns);
  flash_attn_kernel<<<g2, dim3(256), 0, stream>>>(Qb, Kb, Vt, Opart, Lsum,
                                                  NT / ns);

  dim3 g3(BLQ / 64);
  if (ns == 8) {
    combine_out_proj<8><<<g3, dim3(256), 0, stream>>>(Opart, Lsum, WoT, bo, out);
  } else {
    combine_out_proj<4><<<g3, dim3(256), 0, stream>>>(Opart, Lsum, WoT, bo, out);
  }
}

// Round 16
// 97.955 us; speedup vs baseline: 1.8612x; 1.0190x over previous
//
#include <hip/hip_runtime.h>

#define B_SZ 4
#define LQ 4096
#define LKV 4096
#define DIN 256
#define DOUT 128
#define KVBLK 32
#define NT (LKV / KVBLK)
#define BLQ (B_SZ * LQ)
#define KTILE (KVBLK * 128)  // u16 elements per K or V tile (8 KB)

typedef unsigned short u16;
typedef __attribute__((ext_vector_type(8))) short bf16x8;
typedef __attribute__((ext_vector_type(4))) float f32x4;
typedef __attribute__((ext_vector_type(16))) float f32x16;

union Bf8Pack {
  u16 u[8];
  bf16x8 v;
};
union U16x4Pack {
  u16 u[4];
  uint2 v;
};
union PFrag {
  unsigned u[4];
  bf16x8 v;
};

__device__ __forceinline__ u16 f2bf(float x) {
  unsigned u = __float_as_uint(x);
  u += 0x7fffu + ((u >> 16) & 1u);
  return (u16)(u >> 16);
}

__device__ __forceinline__ float bf2f(u16 x) {
  return __uint_as_float(((unsigned)x) << 16);
}

__device__ __forceinline__ unsigned cvt_pk_bf16(float lo, float hi) {
  unsigned r;
  asm("v_cvt_pk_bf16_f32 %0, %1, %2" : "=v"(r) : "v"(lo), "v"(hi));
  return r;
}

__device__ __forceinline__ void gload_lds16(const u16* g, u16* l) {
  __builtin_amdgcn_global_load_lds(
      (__attribute__((address_space(1))) unsigned int*)g,
      (__attribute__((address_space(3))) unsigned int*)l, 16, 0, 0);
}

// ---------- weight transpose + bf16 convert: Wt[3][128][256], WoT[128][128] ----------
__global__ __launch_bounds__(256) void wtrans_kernel(
    const float* __restrict__ Wq, const float* __restrict__ Wk,
    const float* __restrict__ Wv, const float* __restrict__ Wo,
    u16* __restrict__ Wt, u16* __restrict__ WoT) {
  const int gid = blockIdx.x * 256 + threadIdx.x;
  if (gid < 3 * DOUT * DIN) {
    const int which = gid / (DOUT * DIN);
    const int r = gid % (DOUT * DIN);
    const int n = r >> 8;
    const int k = r & 255;
    const float* W = (which == 0) ? Wq : (which == 1) ? Wk : Wv;
    Wt[gid] = f2bf(W[k * DOUT + n]);
  } else {
    const int r = gid - 3 * DOUT * DIN;
    if (r < DOUT * DOUT) {
      const int n = r >> 7;
      const int k = r & 127;
      WoT[r] = f2bf(Wo[k * DOUT + n]);
    }
  }
}

// ---------- QKV projection via MFMA, W staged in LDS (fragment-ordered) ----------
// grid (BLQ/64, 2), block 256. y=0: Q from ligand. y=1: K then V from pocket,
// sharing one sfrag load (pocket read ONCE); Wk staged, K computed, then Wv
// re-staged into the same 64 KB and V computed.
// Fragment f = dt*8+ks lives at Wlds[f*512 + lane*8]: lane (lg,lr) holds
// W^T[dt*16+lr][ks*32+lg*8 ..+8]. Reads are lane*16B -> 0 conflicts.
__global__ __launch_bounds__(256) void qkv_proj_mfma(
    const float* __restrict__ ligand, const float* __restrict__ pocket,
    const float* __restrict__ bq, const float* __restrict__ bk,
    const float* __restrict__ bv, const u16* __restrict__ Wt,
    u16* __restrict__ Qb, u16* __restrict__ Kb, u16* __restrict__ Vt) {
  __shared__ __align__(16) u16 Wlds[DOUT * DIN];  // 64 KB
  const int which = blockIdx.y;
  const int row0 = blockIdx.x * 64;
  const int tid = threadIdx.x;
  const int wid = tid >> 6;
  const int lane = tid & 63;
  const int lg = lane >> 4, lr = lane & 15;

  // staging chunk offsets (fragment order): 4096 x 16B chunks, 16 per thread
  int wsrc[16];
#pragma unroll
  for (int i = 0; i < 16; ++i) {
    const int c = i * 256 + tid;
    const int f = c >> 6;  // dt = f>>3, ks = f&7
    const int l = c & 63;
    wsrc[i] = ((f >> 3) * 16 + (l & 15)) * DIN + (f & 7) * 32 + (l >> 4) * 8;
  }

#define STAGEW(Wsrc)                                                         \
  {                                                                          \
    _Pragma("unroll") for (int i = 0; i < 16; ++i)                           \
        gload_lds16((Wsrc) + wsrc[i], Wlds + (size_t)(i * 256 + tid) * 8);   \
  }

  const float* __restrict__ srcp = (which == 0) ? ligand : pocket;
  const int m = row0 + wid * 16 + lr;

  STAGEW(Wt + (size_t)which * DOUT * DIN);  // Wq or Wk

  bf16x8 sfrag[8];
#pragma unroll
  for (int ks = 0; ks < 8; ++ks) {
    const float* p = srcp + (size_t)m * DIN + ks * 32 + lg * 8;
    const float4 a = *(const float4*)p;
    const float4 b = *(const float4*)(p + 4);
    Bf8Pack pk;
    pk.u[0] = f2bf(a.x); pk.u[1] = f2bf(a.y); pk.u[2] = f2bf(a.z); pk.u[3] = f2bf(a.w);
    pk.u[4] = f2bf(b.x); pk.u[5] = f2bf(b.y); pk.u[6] = f2bf(b.z); pk.u[7] = f2bf(b.w);
    sfrag[ks] = pk.v;
  }

  __syncthreads();  // drains W staging
  const u16* wread = Wlds + lane * 8;

  if (which == 0) {
    // Q pre-scaled by 1/sqrt(128) * log2(e): flash uses exp2 with fixed m=0.
    const float qscale = (float)(0.08838834764831845 * 1.4426950408889634);
#pragma unroll
    for (int dt = 0; dt < 8; ++dt) {
      f32x4 acc = (f32x4){0.f, 0.f, 0.f, 0.f};
#pragma unroll
      for (int ks = 0; ks < 8; ++ks) {
        const bf16x8 wf = *(const bf16x8*)(wread + (dt * 8 + ks) * 512);
        acc = __builtin_amdgcn_mfma_f32_16x16x32_bf16(wf, sfrag[ks], acc, 0, 0, 0);
      }
      U16x4Pack st;
#pragma unroll
      for (int j = 0; j < 4; ++j)
        st.u[j] = f2bf((acc[j] + bq[dt * 16 + lg * 4 + j]) * qscale);
      *(uint2*)(Qb + (size_t)m * DOUT + dt * 16 + lg * 4) = st.v;
    }
  } else {
    // K: C[d][m] orientation, row-major K output
#pragma unroll
    for (int dt = 0; dt < 8; ++dt) {
      f32x4 acc = (f32x4){0.f, 0.f, 0.f, 0.f};
#pragma unroll
      for (int ks = 0; ks < 8; ++ks) {
        const bf16x8 wf = *(const bf16x8*)(wread + (dt * 8 + ks) * 512);
        acc = __builtin_amdgcn_mfma_f32_16x16x32_bf16(wf, sfrag[ks], acc, 0, 0, 0);
      }
      U16x4Pack st;
#pragma unroll
      for (int j = 0; j < 4; ++j) st.u[j] = f2bf(acc[j] + bk[dt * 16 + lg * 4 + j]);
      *(uint2*)(Kb + (size_t)m * DOUT + dt * 16 + lg * 4) = st.v;
    }

    __syncthreads();  // all waves done reading Wk
    STAGEW(Wt + (size_t)2 * DOUT * DIN);  // Wv into same buffer
    __syncthreads();  // Wv staged (drains vmcnt)

    // V: C[m][d] orientation, transposed output V^T[d][kv]
    const int batch = row0 >> 12;
    const int kvbase = (row0 & 4095) + wid * 16 + lg * 4;
#pragma unroll
    for (int dt = 0; dt < 8; ++dt) {
      f32x4 acc = (f32x4){0.f, 0.f, 0.f, 0.f};
#pragma unroll
      for (int ks = 0; ks < 8; ++ks) {
        const bf16x8 wf = *(const bf16x8*)(wread + (dt * 8 + ks) * 512);
        acc = __builtin_amdgcn_mfma_f32_16x16x32_bf16(sfrag[ks], wf, acc, 0, 0, 0);
      }
      const int d = dt * 16 + lr;
      const float b = bv[d];
      U16x4Pack st;
#pragma unroll
      for (int j = 0; j < 4; ++j) st.u[j] = f2bf(acc[j] + b);
      *(uint2*)(Vt + ((size_t)batch * DOUT + d) * LKV + kvbase) = st.v;
    }
  }
#undef STAGEW
}

// ---------------- Flash attention: r8 byte-exact core (32x32x16, P in-register,
// double-buffer, one __syncthreads/iter, shfl_xor row-sum, plain stores).
__global__ __launch_bounds__(256, 4) void flash_attn_kernel(
    const u16* __restrict__ Qb, const u16* __restrict__ Kb,
    const u16* __restrict__ Vt, u16* __restrict__ Opart,
    float* __restrict__ Lsum, int niter) {
  __shared__ __align__(16) u16 Ks[2 * KTILE];
  __shared__ __align__(16) u16 Vs[2 * KTILE];

  const int batch = blockIdx.y;
  const int split = blockIdx.z;
  const int q0 = blockIdx.x * 128;
  const int tid = threadIdx.x;
  const int wid = tid >> 6;
  const int lane = tid & 63;
  const int ql = lane & 31;
  const int h = lane >> 5;
  const int t0 = split * niter;

  // staging source offsets (u16 elements): 512 chunks/tile, 2 per thread
  int koff[2], voff[2];
#pragma unroll
  for (int i = 0; i < 2; ++i) {
    const int c = i * 256 + tid;
    koff[i] = (c & 31) * 128 + (c >> 6) * 16 + ((c >> 5) & 1) * 8;
    voff[i] = ((c >> 7) * 32 + (c & 31)) * LKV + (((c >> 6) & 1) << 4) +
              (((c >> 5) & 1) << 3);
  }
  const u16* KbB = Kb + (size_t)batch * LKV * 128 + (size_t)t0 * KTILE;
  const u16* VtB = Vt + (size_t)batch * 128 * LKV + t0 * KVBLK;

#define STAGEKV(buf, t)                                                      \
  {                                                                          \
    _Pragma("unroll") for (int i = 0; i < 2; ++i)                            \
        gload_lds16(KbB + (t) * KTILE + koff[i],                             \
                    Ks + (buf) * KTILE + (i * 256 + tid) * 8);               \
    _Pragma("unroll") for (int i = 0; i < 2; ++i)                            \
        gload_lds16(VtB + (t) * KVBLK + voff[i],                             \
                    Vs + (buf) * KTILE + (i * 256 + tid) * 8);               \
  }

  // Q fragments: lane holds Q[q0+wid*32+ql][ks*16 + h*8 ..+8], ks=0..7
  const u16* Qw = Qb + ((size_t)batch * LQ + q0 + wid * 32) * 128;
  bf16x8 qf[8];
#pragma unroll
  for (int ks = 0; ks < 8; ++ks)
    qf[ks] = *(const bf16x8*)(Qw + (size_t)ql * 128 + ks * 16 + h * 8);

  f32x16 oacc[4];
#pragma unroll
  for (int dt = 0; dt < 4; ++dt)
#pragma unroll
    for (int r = 0; r < 16; ++r) oacc[dt][r] = 0.f;
  float l_run = 0.f;

  STAGEKV(0, 0);
  __syncthreads();

  int cur = 0;
  for (int t = 0; t < niter; ++t) {
    if (t + 1 < niter) STAGEKV(cur ^ 1, t + 1);

    const u16* kread = Ks + cur * KTILE + lane * 8;
    const u16* vread = Vs + cur * KTILE + lane * 8;

    // S = K · Q^T  (D[kv][q], col q = lane&31)
    f32x16 sacc;
#pragma unroll
    for (int r = 0; r < 16; ++r) sacc[r] = 0.f;
#pragma unroll
    for (int ks = 0; ks < 8; ++ks) {
      const bf16x8 kf = *(const bf16x8*)(kread + ks * 512);
      sacc = __builtin_amdgcn_mfma_f32_32x32x16_bf16(kf, qf[ks], sacc, 0, 0, 0);
    }

    // fixed-m softmax (log2 domain): p = exp2(s); pairwise tree sum
    float p[16];
#pragma unroll
    for (int r = 0; r < 16; ++r) p[r] = exp2f(sacc[r]);
    float rs = (((p[0] + p[1]) + (p[2] + p[3])) + ((p[4] + p[5]) + (p[6] + p[7]))) +
               (((p[8] + p[9]) + (p[10] + p[11])) + ((p[12] + p[13]) + (p[14] + p[15])));
    rs += __shfl_xor(rs, 32, 64);
    l_run += rs;

    // pack P to bf16 pairs, redistribute halves via permlane32_swap
    unsigned w0 = cvt_pk_bf16(p[0], p[1]);
    unsigned w1 = cvt_pk_bf16(p[2], p[3]);
    unsigned w2 = cvt_pk_bf16(p[4], p[5]);
    unsigned w3 = cvt_pk_bf16(p[6], p[7]);
    unsigned w4 = cvt_pk_bf16(p[8], p[9]);
    unsigned w5 = cvt_pk_bf16(p[10], p[11]);
    unsigned w6 = cvt_pk_bf16(p[12], p[13]);
    unsigned w7 = cvt_pk_bf16(p[14], p[15]);
    asm("v_permlane32_swap_b32 %0, %1" : "+v"(w0), "+v"(w2));
    asm("v_permlane32_swap_b32 %0, %1" : "+v"(w1), "+v"(w3));
    asm("v_permlane32_swap_b32 %0, %1" : "+v"(w4), "+v"(w6));
    asm("v_permlane32_swap_b32 %0, %1" : "+v"(w5), "+v"(w7));
    PFrag pa0, pa1;
    pa0.u[0] = w0; pa0.u[1] = w1; pa0.u[2] = w2; pa0.u[3] = w3;  // kv 0..15
    pa1.u[0] = w4; pa1.u[1] = w5; pa1.u[2] = w6; pa1.u[3] = w7;  // kv 16..31

    // O^T += V^T · P^T
#pragma unroll
    for (int dt = 0; dt < 4; ++dt) {
      const bf16x8 vf0 = *(const bf16x8*)(vread + (dt * 2 + 0) * 512);
      oacc[dt] = __builtin_amdgcn_mfma_f32_32x32x16_bf16(vf0, pa0.v, oacc[dt], 0, 0, 0);
      const bf16x8 vf1 = *(const bf16x8*)(vread + (dt * 2 + 1) * 512);
      oacc[dt] = __builtin_amdgcn_mfma_f32_32x32x16_bf16(vf1, pa1.v, oacc[dt], 0, 0, 0);
    }

    __syncthreads();
    cur ^= 1;
  }

  // write bf16 unnormalized partials + row sums (m = 0 global)
  const size_t rowbase = (size_t)split * BLQ + (size_t)batch * LQ + q0 + wid * 32;
  u16* Op = Opart + (rowbase + ql) * 128;
#pragma unroll
  for (int dt = 0; dt < 4; ++dt)
#pragma unroll
    for (int g2 = 0; g2 < 4; ++g2) {
      uint2 st;
      st.x = cvt_pk_bf16(oacc[dt][g2 * 4 + 0], oacc[dt][g2 * 4 + 1]);
      st.y = cvt_pk_bf16(oacc[dt][g2 * 4 + 2], oacc[dt][g2 * 4 + 3]);
      *(uint2*)(Op + dt * 32 + g2 * 8 + h * 4) = st;
    }
  if (lane < 32) Lsum[rowbase + lane] = l_run;
#undef STAGEKV
}

// ---------- combine KV-splits (linear, m=0) + output projection via MFMA ----------
template <int NS>
__global__ __launch_bounds__(256) void combine_out_proj(
    const u16* __restrict__ Opart, const float* __restrict__ Lsum,
    const u16* __restrict__ WoT, const float* __restrict__ bo,
    float* __restrict__ out) {
  const int row0 = blockIdx.x * 64;
  const int tid = threadIdx.x;
  const int wid = tid >> 6;
  const int lane = tid & 63;
  const int lg = lane >> 4, lr = lane & 15;
  const int m = row0 + wid * 16 + lr;

  float den = 0.f;
#pragma unroll
  for (int s = 0; s < NS; ++s) den += Lsum[(size_t)s * BLQ + m];
  const float inv = 1.f / den;

  float accO[4][8];
#pragma unroll
  for (int ks = 0; ks < 4; ++ks)
#pragma unroll
    for (int j = 0; j < 8; ++j) accO[ks][j] = 0.f;

#pragma unroll
  for (int s = 0; s < NS; ++s) {
    const u16* Op = Opart + ((size_t)s * BLQ + m) * 128;
#pragma unroll
    for (int ks = 0; ks < 4; ++ks) {
      const uint4 v = *(const uint4*)(Op + ks * 32 + lg * 8);
      accO[ks][0] += bf2f((u16)(v.x & 0xffff));
      accO[ks][1] += bf2f((u16)(v.x >> 16));
      accO[ks][2] += bf2f((u16)(v.y & 0xffff));
      accO[ks][3] += bf2f((u16)(v.y >> 16));
      accO[ks][4] += bf2f((u16)(v.z & 0xffff));
      accO[ks][5] += bf2f((u16)(v.z >> 16));
      accO[ks][6] += bf2f((u16)(v.w & 0xffff));
      accO[ks][7] += bf2f((u16)(v.w >> 16));
    }
  }

  bf16x8 ofrag[4];
#pragma unroll
  for (int ks = 0; ks < 4; ++ks) {
    Bf8Pack pk;
#pragma unroll
    for (int j = 0; j < 8; ++j) pk.u[j] = f2bf(accO[ks][j] * inv);
    ofrag[ks] = pk.v;
  }

#pragma unroll
  for (int dt = 0; dt < 8; ++dt) {
    f32x4 acc = (f32x4){0.f, 0.f, 0.f, 0.f};
#pragma unroll
    for (int ks = 0; ks < 4; ++ks) {
      const bf16x8 wf =
          *(const bf16x8*)(WoT + (size_t)(dt * 16 + lr) * DOUT + ks * 32 + lg * 8);
      acc = __builtin_amdgcn_mfma_f32_16x16x32_bf16(wf, ofrag[ks], acc, 0, 0, 0);
    }
    float4 o;
    o.x = acc[0] + bo[dt * 16 + lg * 4 + 0];
    o.y = acc[1] + bo[dt * 16 + lg * 4 + 1];
    o.z = acc[2] + bo[dt * 16 + lg * 4 + 2];
    o.w = acc[3] + bo[dt * 16 + lg * 4 + 3];
    *(float4*)(out + (size_t)m * DOUT + dt * 16 + lg * 4) = o;
  }
}

extern "C" void kernel_launch(void* const* d_in, const int* in_sizes, int n_in,
                              void* d_out, int out_size, void* d_ws,
                              size_t ws_size, hipStream_t stream) {
  const float* ligand = (const float*)d_in[0];
  const float* pocket = (const float*)d_in[1];
  const float* Wq = (const float*)d_in[2];
  const float* bq = (const float*)d_in[3];
  const float* Wk = (const float*)d_in[4];
  const float* bk = (const float*)d_in[5];
  const float* Wv = (const float*)d_in[6];
  const float* bv = (const float*)d_in[7];
  const float* Wo = (const float*)d_in[8];
  const float* bo = (const float*)d_in[9];
  float* out = (float*)d_out;

  const size_t MB = 1024 * 1024;
  char* ws = (char*)d_ws;
  u16* Qb = (u16*)(ws);                      // 4 MB
  u16* Kb = (u16*)(ws + 4 * MB);             // 4 MB
  u16* Vt = (u16*)(ws + 8 * MB);             // 4 MB (V^T)
  u16* Wt = (u16*)(ws + 12 * MB);            // 192 KB
  u16* WoT = Wt + 3 * DOUT * DIN;            // 32 KB
  const int ns = (ws_size >= 46 * MB) ? 8 : 4;
  u16* Opart = (u16*)(ws + 13 * MB);                            // ns*4 MB bf16
  float* Lsum = (float*)(ws + 13 * MB + (size_t)ns * 4 * MB);   // ns*64 KB

  wtrans_kernel<<<dim3(448), dim3(256), 0, stream>>>(Wq, Wk, Wv, Wo, Wt, WoT);

  dim3 g1(BLQ / 64, 2);
  qkv_proj_mfma<<<g1, dim3(256), 0, stream>>>(ligand, pocket, bq, bk, bv, Wt,
                                              Qb, Kb, Vt);

  dim3 g2(LQ / 128, B_SZ, ns);
  flash_attn_kernel<<<g2, dim3(256), 0, stream>>>(Qb, Kb, Vt, Opart, Lsum,
                                                  NT / ns);

  dim3 g3(BLQ / 64);
  if (ns == 8) {
    combine_out_proj<8><<<g3, dim3(256), 0, stream>>>(Opart, Lsum, WoT, bo, out);
  } else {
    combine_out_proj<4><<<g3, dim3(256), 0, stream>>>(Opart, Lsum, WoT, bo, out);
  }
}

// Round 17
// 92.505 us; speedup vs baseline: 1.9709x; 1.0589x over previous
//
#include <hip/hip_runtime.h>

#define B_SZ 4
#define LQ 4096
#define LKV 4096
#define DIN 256
#define DOUT 128
#define KVBLK 32
#define NT (LKV / KVBLK)
#define BLQ (B_SZ * LQ)
#define KTILE (KVBLK * 128)  // u16 elements per K or V tile (8 KB)

typedef unsigned short u16;
typedef __attribute__((ext_vector_type(8))) short bf16x8;
typedef __attribute__((ext_vector_type(4))) float f32x4;
typedef __attribute__((ext_vector_type(16))) float f32x16;

union Bf8Pack {
  u16 u[8];
  bf16x8 v;
};
union U16x4Pack {
  u16 u[4];
  uint2 v;
};
union PFrag {
  unsigned u[4];
  bf16x8 v;
};

__device__ __forceinline__ u16 f2bf(float x) {
  unsigned u = __float_as_uint(x);
  u += 0x7fffu + ((u >> 16) & 1u);
  return (u16)(u >> 16);
}

__device__ __forceinline__ float bf2f(u16 x) {
  return __uint_as_float(((unsigned)x) << 16);
}

__device__ __forceinline__ unsigned cvt_pk_bf16(float lo, float hi) {
  unsigned r;
  asm("v_cvt_pk_bf16_f32 %0, %1, %2" : "=v"(r) : "v"(lo), "v"(hi));
  return r;
}

__device__ __forceinline__ void gload_lds16(const u16* g, u16* l) {
  __builtin_amdgcn_global_load_lds(
      (__attribute__((address_space(1))) unsigned int*)g,
      (__attribute__((address_space(3))) unsigned int*)l, 16, 0, 0);
}

// ---------- weight transpose + bf16 convert: Wt[3][128][256], WoT[128][128] ----------
__global__ __launch_bounds__(256) void wtrans_kernel(
    const float* __restrict__ Wq, const float* __restrict__ Wk,
    const float* __restrict__ Wv, const float* __restrict__ Wo,
    u16* __restrict__ Wt, u16* __restrict__ WoT) {
  const int gid = blockIdx.x * 256 + threadIdx.x;
  if (gid < 3 * DOUT * DIN) {
    const int which = gid / (DOUT * DIN);
    const int r = gid % (DOUT * DIN);
    const int n = r >> 8;
    const int k = r & 255;
    const float* W = (which == 0) ? Wq : (which == 1) ? Wk : Wv;
    Wt[gid] = f2bf(W[k * DOUT + n]);
  } else {
    const int r = gid - 3 * DOUT * DIN;
    if (r < DOUT * DOUT) {
      const int n = r >> 7;
      const int k = r & 127;
      WoT[r] = f2bf(Wo[k * DOUT + n]);
    }
  }
}

// ---------- QKV projection via MFMA, W staged in LDS (fragment-ordered) ----------
// grid (BLQ/64, 2), block 256. y=0: Q from ligand. y=1: K then V from pocket,
// sharing one sfrag load (pocket read ONCE); Wk staged, K computed, then Wv
// re-staged into the same 64 KB and V computed.
__global__ __launch_bounds__(256) void qkv_proj_mfma(
    const float* __restrict__ ligand, const float* __restrict__ pocket,
    const float* __restrict__ bq, const float* __restrict__ bk,
    const float* __restrict__ bv, const u16* __restrict__ Wt,
    u16* __restrict__ Qb, u16* __restrict__ Kb, u16* __restrict__ Vt) {
  __shared__ __align__(16) u16 Wlds[DOUT * DIN];  // 64 KB
  const int which = blockIdx.y;
  const int row0 = blockIdx.x * 64;
  const int tid = threadIdx.x;
  const int wid = tid >> 6;
  const int lane = tid & 63;
  const int lg = lane >> 4, lr = lane & 15;

  // staging chunk offsets (fragment order): 4096 x 16B chunks, 16 per thread
  int wsrc[16];
#pragma unroll
  for (int i = 0; i < 16; ++i) {
    const int c = i * 256 + tid;
    const int f = c >> 6;  // dt = f>>3, ks = f&7
    const int l = c & 63;
    wsrc[i] = ((f >> 3) * 16 + (l & 15)) * DIN + (f & 7) * 32 + (l >> 4) * 8;
  }

#define STAGEW(Wsrc)                                                         \
  {                                                                          \
    _Pragma("unroll") for (int i = 0; i < 16; ++i)                           \
        gload_lds16((Wsrc) + wsrc[i], Wlds + (size_t)(i * 256 + tid) * 8);   \
  }

  const float* __restrict__ srcp = (which == 0) ? ligand : pocket;
  const int m = row0 + wid * 16 + lr;

  STAGEW(Wt + (size_t)which * DOUT * DIN);  // Wq or Wk

  bf16x8 sfrag[8];
#pragma unroll
  for (int ks = 0; ks < 8; ++ks) {
    const float* p = srcp + (size_t)m * DIN + ks * 32 + lg * 8;
    const float4 a = *(const float4*)p;
    const float4 b = *(const float4*)(p + 4);
    Bf8Pack pk;
    pk.u[0] = f2bf(a.x); pk.u[1] = f2bf(a.y); pk.u[2] = f2bf(a.z); pk.u[3] = f2bf(a.w);
    pk.u[4] = f2bf(b.x); pk.u[5] = f2bf(b.y); pk.u[6] = f2bf(b.z); pk.u[7] = f2bf(b.w);
    sfrag[ks] = pk.v;
  }

  __syncthreads();  // drains W staging
  const u16* wread = Wlds + lane * 8;

  if (which == 0) {
    // Q pre-scaled by 1/sqrt(128) * log2(e): flash uses exp2 with fixed m=0.
    const float qscale = (float)(0.08838834764831845 * 1.4426950408889634);
#pragma unroll
    for (int dt = 0; dt < 8; ++dt) {
      f32x4 acc = (f32x4){0.f, 0.f, 0.f, 0.f};
#pragma unroll
      for (int ks = 0; ks < 8; ++ks) {
        const bf16x8 wf = *(const bf16x8*)(wread + (dt * 8 + ks) * 512);
        acc = __builtin_amdgcn_mfma_f32_16x16x32_bf16(wf, sfrag[ks], acc, 0, 0, 0);
      }
      U16x4Pack st;
#pragma unroll
      for (int j = 0; j < 4; ++j)
        st.u[j] = f2bf((acc[j] + bq[dt * 16 + lg * 4 + j]) * qscale);
      *(uint2*)(Qb + (size_t)m * DOUT + dt * 16 + lg * 4) = st.v;
    }
  } else {
    // K: C[d][m] orientation, row-major K output
#pragma unroll
    for (int dt = 0; dt < 8; ++dt) {
      f32x4 acc = (f32x4){0.f, 0.f, 0.f, 0.f};
#pragma unroll
      for (int ks = 0; ks < 8; ++ks) {
        const bf16x8 wf = *(const bf16x8*)(wread + (dt * 8 + ks) * 512);
        acc = __builtin_amdgcn_mfma_f32_16x16x32_bf16(wf, sfrag[ks], acc, 0, 0, 0);
      }
      U16x4Pack st;
#pragma unroll
      for (int j = 0; j < 4; ++j) st.u[j] = f2bf(acc[j] + bk[dt * 16 + lg * 4 + j]);
      *(uint2*)(Kb + (size_t)m * DOUT + dt * 16 + lg * 4) = st.v;
    }

    __syncthreads();  // all waves done reading Wk
    STAGEW(Wt + (size_t)2 * DOUT * DIN);  // Wv into same buffer
    __syncthreads();  // Wv staged (drains vmcnt)

    // V: C[m][d] orientation, transposed output V^T[d][kv]
    const int batch = row0 >> 12;
    const int kvbase = (row0 & 4095) + wid * 16 + lg * 4;
#pragma unroll
    for (int dt = 0; dt < 8; ++dt) {
      f32x4 acc = (f32x4){0.f, 0.f, 0.f, 0.f};
#pragma unroll
      for (int ks = 0; ks < 8; ++ks) {
        const bf16x8 wf = *(const bf16x8*)(wread + (dt * 8 + ks) * 512);
        acc = __builtin_amdgcn_mfma_f32_16x16x32_bf16(sfrag[ks], wf, acc, 0, 0, 0);
      }
      const int d = dt * 16 + lr;
      const float b = bv[d];
      U16x4Pack st;
#pragma unroll
      for (int j = 0; j < 4; ++j) st.u[j] = f2bf(acc[j] + b);
      *(uint2*)(Vt + ((size_t)batch * DOUT + d) * LKV + kvbase) = st.v;
    }
  }
#undef STAGEW
}

// ---------------- Flash attention: r8 per-wave core, 8-wave blocks (QBLK=256).
// 512 threads = 8 waves x 32 q-rows; 2 blocks/CU -> 4 waves/SIMD from 2 blocks
// (cross-block latency hiding). K/V staged once per 256 q-rows (traffic halved).
__global__ __launch_bounds__(512, 4) void flash_attn_kernel(
    const u16* __restrict__ Qb, const u16* __restrict__ Kb,
    const u16* __restrict__ Vt, u16* __restrict__ Opart,
    float* __restrict__ Lsum, int niter) {
  __shared__ __align__(16) u16 Ks[2 * KTILE];
  __shared__ __align__(16) u16 Vs[2 * KTILE];

  const int batch = blockIdx.y;
  const int split = blockIdx.z;
  const int q0 = blockIdx.x * 256;
  const int tid = threadIdx.x;
  const int wid = tid >> 6;  // 0..7
  const int lane = tid & 63;
  const int ql = lane & 31;
  const int h = lane >> 5;
  const int t0 = split * niter;

  // staging source offsets (u16 elements): 512 chunks/tile, 1 per thread
  const int ck = tid;
  const int koff = (ck & 31) * 128 + (ck >> 6) * 16 + ((ck >> 5) & 1) * 8;
  const int voff = ((ck >> 7) * 32 + (ck & 31)) * LKV + (((ck >> 6) & 1) << 4) +
                   (((ck >> 5) & 1) << 3);
  const u16* KbB = Kb + (size_t)batch * LKV * 128 + (size_t)t0 * KTILE;
  const u16* VtB = Vt + (size_t)batch * 128 * LKV + t0 * KVBLK;

#define STAGEKV(buf, t)                                                      \
  {                                                                          \
    gload_lds16(KbB + (t) * KTILE + koff, Ks + (buf) * KTILE + tid * 8);     \
    gload_lds16(VtB + (t) * KVBLK + voff, Vs + (buf) * KTILE + tid * 8);     \
  }

  // Q fragments: lane holds Q[q0+wid*32+ql][ks*16 + h*8 ..+8], ks=0..7
  const u16* Qw = Qb + ((size_t)batch * LQ + q0 + wid * 32) * 128;
  bf16x8 qf[8];
#pragma unroll
  for (int ks = 0; ks < 8; ++ks)
    qf[ks] = *(const bf16x8*)(Qw + (size_t)ql * 128 + ks * 16 + h * 8);

  f32x16 oacc[4];
#pragma unroll
  for (int dt = 0; dt < 4; ++dt)
#pragma unroll
    for (int r = 0; r < 16; ++r) oacc[dt][r] = 0.f;
  float l_run = 0.f;

  STAGEKV(0, 0);
  __syncthreads();

  int cur = 0;
  for (int t = 0; t < niter; ++t) {
    if (t + 1 < niter) STAGEKV(cur ^ 1, t + 1);

    const u16* kread = Ks + cur * KTILE + lane * 8;
    const u16* vread = Vs + cur * KTILE + lane * 8;

    // S = K · Q^T  (D[kv][q], col q = lane&31)
    f32x16 sacc;
#pragma unroll
    for (int r = 0; r < 16; ++r) sacc[r] = 0.f;
#pragma unroll
    for (int ks = 0; ks < 8; ++ks) {
      const bf16x8 kf = *(const bf16x8*)(kread + ks * 512);
      sacc = __builtin_amdgcn_mfma_f32_32x32x16_bf16(kf, qf[ks], sacc, 0, 0, 0);
    }

    // fixed-m softmax (log2 domain): p = exp2(s); pairwise tree sum
    float p[16];
#pragma unroll
    for (int r = 0; r < 16; ++r) p[r] = exp2f(sacc[r]);
    float rs = (((p[0] + p[1]) + (p[2] + p[3])) + ((p[4] + p[5]) + (p[6] + p[7]))) +
               (((p[8] + p[9]) + (p[10] + p[11])) + ((p[12] + p[13]) + (p[14] + p[15])));
    rs += __shfl_xor(rs, 32, 64);
    l_run += rs;

    // pack P to bf16 pairs, redistribute halves via permlane32_swap
    unsigned w0 = cvt_pk_bf16(p[0], p[1]);
    unsigned w1 = cvt_pk_bf16(p[2], p[3]);
    unsigned w2 = cvt_pk_bf16(p[4], p[5]);
    unsigned w3 = cvt_pk_bf16(p[6], p[7]);
    unsigned w4 = cvt_pk_bf16(p[8], p[9]);
    unsigned w5 = cvt_pk_bf16(p[10], p[11]);
    unsigned w6 = cvt_pk_bf16(p[12], p[13]);
    unsigned w7 = cvt_pk_bf16(p[14], p[15]);
    asm("v_permlane32_swap_b32 %0, %1" : "+v"(w0), "+v"(w2));
    asm("v_permlane32_swap_b32 %0, %1" : "+v"(w1), "+v"(w3));
    asm("v_permlane32_swap_b32 %0, %1" : "+v"(w4), "+v"(w6));
    asm("v_permlane32_swap_b32 %0, %1" : "+v"(w5), "+v"(w7));
    PFrag pa0, pa1;
    pa0.u[0] = w0; pa0.u[1] = w1; pa0.u[2] = w2; pa0.u[3] = w3;  // kv 0..15
    pa1.u[0] = w4; pa1.u[1] = w5; pa1.u[2] = w6; pa1.u[3] = w7;  // kv 16..31

    // O^T += V^T · P^T
#pragma unroll
    for (int dt = 0; dt < 4; ++dt) {
      const bf16x8 vf0 = *(const bf16x8*)(vread + (dt * 2 + 0) * 512);
      oacc[dt] = __builtin_amdgcn_mfma_f32_32x32x16_bf16(vf0, pa0.v, oacc[dt], 0, 0, 0);
      const bf16x8 vf1 = *(const bf16x8*)(vread + (dt * 2 + 1) * 512);
      oacc[dt] = __builtin_amdgcn_mfma_f32_32x32x16_bf16(vf1, pa1.v, oacc[dt], 0, 0, 0);
    }

    __syncthreads();
    cur ^= 1;
  }

  // write bf16 unnormalized partials + row sums (m = 0 global)
  const size_t rowbase = (size_t)split * BLQ + (size_t)batch * LQ + q0 + wid * 32;
  u16* Op = Opart + (rowbase + ql) * 128;
#pragma unroll
  for (int dt = 0; dt < 4; ++dt)
#pragma unroll
    for (int g2 = 0; g2 < 4; ++g2) {
      uint2 st;
      st.x = cvt_pk_bf16(oacc[dt][g2 * 4 + 0], oacc[dt][g2 * 4 + 1]);
      st.y = cvt_pk_bf16(oacc[dt][g2 * 4 + 2], oacc[dt][g2 * 4 + 3]);
      *(uint2*)(Op + dt * 32 + g2 * 8 + h * 4) = st;
    }
  if (lane < 32) Lsum[rowbase + lane] = l_run;
#undef STAGEKV
}

// ---------- combine KV-splits (linear, m=0) + output projection via MFMA ----------
template <int NS>
__global__ __launch_bounds__(256) void combine_out_proj(
    const u16* __restrict__ Opart, const float* __restrict__ Lsum,
    const u16* __restrict__ WoT, const float* __restrict__ bo,
    float* __restrict__ out) {
  const int row0 = blockIdx.x * 64;
  const int tid = threadIdx.x;
  const int wid = tid >> 6;
  const int lane = tid & 63;
  const int lg = lane >> 4, lr = lane & 15;
  const int m = row0 + wid * 16 + lr;

  float den = 0.f;
#pragma unroll
  for (int s = 0; s < NS; ++s) den += Lsum[(size_t)s * BLQ + m];
  const float inv = 1.f / den;

  float accO[4][8];
#pragma unroll
  for (int ks = 0; ks < 4; ++ks)
#pragma unroll
    for (int j = 0; j < 8; ++j) accO[ks][j] = 0.f;

#pragma unroll
  for (int s = 0; s < NS; ++s) {
    const u16* Op = Opart + ((size_t)s * BLQ + m) * 128;
#pragma unroll
    for (int ks = 0; ks < 4; ++ks) {
      const uint4 v = *(const uint4*)(Op + ks * 32 + lg * 8);
      accO[ks][0] += bf2f((u16)(v.x & 0xffff));
      accO[ks][1] += bf2f((u16)(v.x >> 16));
      accO[ks][2] += bf2f((u16)(v.y & 0xffff));
      accO[ks][3] += bf2f((u16)(v.y >> 16));
      accO[ks][4] += bf2f((u16)(v.z & 0xffff));
      accO[ks][5] += bf2f((u16)(v.z >> 16));
      accO[ks][6] += bf2f((u16)(v.w & 0xffff));
      accO[ks][7] += bf2f((u16)(v.w >> 16));
    }
  }

  bf16x8 ofrag[4];
#pragma unroll
  for (int ks = 0; ks < 4; ++ks) {
    Bf8Pack pk;
#pragma unroll
    for (int j = 0; j < 8; ++j) pk.u[j] = f2bf(accO[ks][j] * inv);
    ofrag[ks] = pk.v;
  }

#pragma unroll
  for (int dt = 0; dt < 8; ++dt) {
    f32x4 acc = (f32x4){0.f, 0.f, 0.f, 0.f};
#pragma unroll
    for (int ks = 0; ks < 4; ++ks) {
      const bf16x8 wf =
          *(const bf16x8*)(WoT + (size_t)(dt * 16 + lr) * DOUT + ks * 32 + lg * 8);
      acc = __builtin_amdgcn_mfma_f32_16x16x32_bf16(wf, ofrag[ks], acc, 0, 0, 0);
    }
    float4 o;
    o.x = acc[0] + bo[dt * 16 + lg * 4 + 0];
    o.y = acc[1] + bo[dt * 16 + lg * 4 + 1];
    o.z = acc[2] + bo[dt * 16 + lg * 4 + 2];
    o.w = acc[3] + bo[dt * 16 + lg * 4 + 3];
    *(float4*)(out + (size_t)m * DOUT + dt * 16 + lg * 4) = o;
  }
}

extern "C" void kernel_launch(void* const* d_in, const int* in_sizes, int n_in,
                              void* d_out, int out_size, void* d_ws,
                              size_t ws_size, hipStream_t stream) {
  const float* ligand = (const float*)d_in[0];
  const float* pocket = (const float*)d_in[1];
  const float* Wq = (const float*)d_in[2];
  const float* bq = (const float*)d_in[3];
  const float* Wk = (const float*)d_in[4];
  const float* bk = (const float*)d_in[5];
  const float* Wv = (const float*)d_in[6];
  const float* bv = (const float*)d_in[7];
  const float* Wo = (const float*)d_in[8];
  const float* bo = (const float*)d_in[9];
  float* out = (float*)d_out;

  const size_t MB = 1024 * 1024;
  char* ws = (char*)d_ws;
  u16* Qb = (u16*)(ws);                      // 4 MB
  u16* Kb = (u16*)(ws + 4 * MB);             // 4 MB
  u16* Vt = (u16*)(ws + 8 * MB);             // 4 MB (V^T)
  u16* Wt = (u16*)(ws + 12 * MB);            // 192 KB
  u16* WoT = Wt + 3 * DOUT * DIN;            // 32 KB
  const int ns = (ws_size >= 46 * MB) ? 8 : 4;
  u16* Opart = (u16*)(ws + 13 * MB);                            // ns*4 MB bf16
  float* Lsum = (float*)(ws + 13 * MB + (size_t)ns * 4 * MB);   // ns*64 KB

  wtrans_kernel<<<dim3(448), dim3(256), 0, stream>>>(Wq, Wk, Wv, Wo, Wt, WoT);

  dim3 g1(BLQ / 64, 2);
  qkv_proj_mfma<<<g1, dim3(256), 0, stream>>>(ligand, pocket, bq, bk, bv, Wt,
                                              Qb, Kb, Vt);

  dim3 g2(LQ / 256, B_SZ, ns);
  flash_attn_kernel<<<g2, dim3(512), 0, stream>>>(Qb, Kb, Vt, Opart, Lsum,
                                                  NT / ns);

  dim3 g3(BLQ / 64);
  if (ns == 8) {
    combine_out_proj<8><<<g3, dim3(256), 0, stream>>>(Opart, Lsum, WoT, bo, out);
  } else {
    combine_out_proj<4><<<g3, dim3(256), 0, stream>>>(Opart, Lsum, WoT, bo, out);
  }
}